// Round 17
// baseline (324.826 us; speedup 1.0000x reference)
//
#include <hip/hip_runtime.h>

#define NN 100000
#define NE 1600000
#define NG 512

#define BSH 9                         // bucket = dst >> 9 (512 nodes/bucket)
#define NB 196                        // ceil(NN / 512)
#define EPB 8192                      // edges per block in phase A
#define NAB ((NE + EPB - 1) / EPB)    // 196 phase-A blocks
#define CAPB 9216                     // fixed bucket capacity (mean 8192, sigma~90)
#define CAP 9216                      // LDS staging capacity in kB_build

// ---------- embedding lookup + pre-linear + relu: x1[N,32] ----------
__global__ __launch_bounds__(256) void k_embed(
    const int* __restrict__ nf, const float* __restrict__ semb,
    const float* __restrict__ cemb, const float* __restrict__ pw,
    const float* __restrict__ pb, float* __restrict__ x1)
{
  int gid = blockIdx.x * 256 + threadIdx.x;
  bool valid = gid < NN;
  int i = valid ? gid : NN - 1;
  int sf = nf[2 * i], cf = nf[2 * i + 1];
  float x0[16];
#pragma unroll
  for (int k = 0; k < 8; ++k) x0[k] = semb[sf * 8 + k];
#pragma unroll
  for (int k = 0; k < 8; ++k) x0[8 + k] = cemb[cf * 8 + k];
  float acc[32];
#pragma unroll
  for (int j = 0; j < 32; ++j) acc[j] = pb[j];
#pragma unroll
  for (int k = 0; k < 16; ++k) {
    float xv = x0[k];
#pragma unroll
    for (int j = 0; j < 32; ++j) acc[j] += xv * pw[k * 32 + j];
  }
  if (valid) {
    float4* o = (float4*)(x1 + (size_t)i * 32);
#pragma unroll
    for (int j4 = 0; j4 < 8; ++j4) {
      float4 v;
      v.x = fmaxf(acc[4 * j4 + 0], 0.f);
      v.y = fmaxf(acc[4 * j4 + 1], 0.f);
      v.z = fmaxf(acc[4 * j4 + 2], 0.f);
      v.w = fmaxf(acc[4 * j4 + 3], 0.f);
      o[j4] = v;
    }
  }
}

// ---------- CSR build: padded-bucket counting sort ----------
// pack: src(0-16) | type(17-18) | dst&511 (19-27)
__global__ __launch_bounds__(256) void kA_scatter(
    const int* __restrict__ ei, const int* __restrict__ et,
    int* __restrict__ bkt_cur, int* __restrict__ binned)
{
  __shared__ int packA[EPB];
  __shared__ unsigned char bktA[EPB];
  __shared__ int lh[NB], grun[NB], lcur[NB];
  for (int b = threadIdx.x; b < NB; b += 256) { lh[b] = 0; lcur[b] = 0; }
  __syncthreads();
  int base = blockIdx.x * EPB;
#pragma unroll
  for (int i = 0; i < EPB / 256; ++i) {
    int p = i * 256 + threadIdx.x;
    int e = base + p;
    if (e < NE) {
      int src = ei[e], dst = ei[NE + e], ty = et[e];
      int b = dst >> BSH;
      packA[p] = src | (ty << 17) | ((dst & 511) << 19);
      bktA[p] = (unsigned char)b;
      atomicAdd(&lh[b], 1);
    } else {
      bktA[p] = 255;
    }
  }
  __syncthreads();
  for (int b = threadIdx.x; b < NB; b += 256)
    grun[b] = lh[b] ? atomicAdd(&bkt_cur[b], lh[b]) : 0;
  __syncthreads();
#pragma unroll
  for (int i = 0; i < EPB / 256; ++i) {
    int p = i * 256 + threadIdx.x;
    int b = bktA[p];
    if (b != 255) {
      int off = grun[b] + atomicAdd(&lcur[b], 1);
      if (off < CAPB) binned[b * CAPB + off] = packA[p];
    }
  }
}

// Phase B: one workgroup per bucket; key = dst_local*3 + type -> per-node
// edge list sorted by relation; rs4[d*4+r] run starts, rs4[d*4+3] run end.
__global__ __launch_bounds__(512) void kB_build(
    const int* __restrict__ bkt_cur, const int* __restrict__ binned,
    int* __restrict__ rs4, int* __restrict__ ep)
{
  __shared__ int stage[CAP];
  __shared__ int ldeg3[1536], lrs3[1536], lcur3[1536];
  __shared__ int sm[2][512];
  int b = blockIdx.x;
  int t = threadIdx.x;
  int p0 = b * CAPB;
  int cnt = bkt_cur[b];
  if (cnt > CAPB) cnt = CAPB;
  int nodes0 = b << BSH;
  int nnodes = NN - nodes0 < 512 ? NN - nodes0 : 512;
  ldeg3[t] = 0; ldeg3[t + 512] = 0; ldeg3[t + 1024] = 0;
  lcur3[t] = 0; lcur3[t + 512] = 0; lcur3[t + 1024] = 0;
  __syncthreads();
  for (int p = t; p < cnt; p += 512) {
    int pk = binned[p0 + p];
    if (p < CAP) stage[p] = pk;
    int key = ((pk >> 19) & 511) * 3 + ((pk >> 17) & 3);
    atomicAdd(&ldeg3[key], 1);
  }
  __syncthreads();
  int s0 = ldeg3[3 * t], s1 = ldeg3[3 * t + 1], s2 = ldeg3[3 * t + 2];
  int tot = s0 + s1 + s2;
  sm[0][t] = tot;
  __syncthreads();
  int cur = 0;
#pragma unroll
  for (int off = 1; off < 512; off <<= 1) {
    int add = (t >= off) ? sm[cur][t - off] : 0;
    sm[cur ^ 1][t] = sm[cur][t] + add;
    __syncthreads();
    cur ^= 1;
  }
  int ex = sm[cur][t] - tot;  // exclusive
  int r0 = p0 + ex, r1 = r0 + s0, r2 = r1 + s1;
  lrs3[3 * t] = r0;
  lrs3[3 * t + 1] = r1;
  lrs3[3 * t + 2] = r2;
  if (t < nnodes) {
    *(int4*)(rs4 + (size_t)4 * (nodes0 + t)) = make_int4(r0, r1, r2, r2 + s2);
  }
  __syncthreads();
  for (int p = t; p < cnt; p += 512) {
    int pk = (p < CAP) ? stage[p] : binned[p0 + p];
    int key = ((pk >> 19) & 511) * 3 + ((pk >> 17) & 3);
    int off = atomicAdd(&lcur3[key], 1);
    ep[lrs3[key] + off] = pk & 0x1FFFF;  // src only
  }
}

// ---------- FUSED agg + dense: y[d] = relu(x[d]@root + b + sum_r mean_r@rel_r) ----
// R17: 2-dst software pipelining in phase A. R16 fixed occupancy (32
// waves/CU) but VALU stuck at 65%: each wave ran its 8 dsts SERIALLY --
// only 4 gathers in flight per wave, and each dst's shfl-reduce tail
// serializes before the next dst's chain starts. VGPR was 28 (budget 64
// at 8 waves/SIMD), so pair dsts and interleave their loops: 2 epv chunk
// regs, 6 accumulators, 2 independent gathers per iteration -> unroll 4
// = 8 gathers in flight; the two reduce tails are independent chains too.
// Length mismatch handled by masks (val=0 slots); over-read of ep stays in
// the zero-padded buffer so e is always a valid id or 0 (no NaN through
// fmaf(0,.)). Phase B unchanged from R16 (rotating 2-stream LDS + h2 spill).
template <int IN>
__global__ __launch_bounds__(512, 8) void k_fused(
    const float* __restrict__ x, const int* __restrict__ rs4,
    const int* __restrict__ ep, const float* __restrict__ root,
    const float* __restrict__ rel, const float* __restrict__ bias,
    float* __restrict__ h2, float* __restrict__ y)
{
  __shared__ float smem[2 * IN][65];
  const int tid = threadIdx.x;
  const int node0 = blockIdx.x * 64;
  const int wv = tid >> 6;
  const int lane = tid & 63;

  constexpr int LPE = IN / 4;              // lanes per edge-row (16 or 8)
  constexpr int DPW = (IN == 32) ? 2 : 1;  // dsts per wave-iteration
  constexpr int SW = 64 / DPW;             // lanes per dst (64 or 32)
  constexpr int EPI = SW / LPE;            // 4 edges per iteration
  const int sub = (IN == 64) ? 0 : (lane >> 5);
  const int sl = lane & (SW - 1);
  const int k4 = sl % LPE;                 // float4 column within row
  const int es = sl / LPE;                 // edge slot 0..3
  const int subBase = lane & ~(SW - 1);

  // ========== Phase A: paired-dst interleaved gather; a0/a1->LDS, a2->h2 ====
  for (int itp = 0; itp < 4 / DPW; ++itp) {
    int dlA = wv * 8 + (2 * itp) * DPW + sub;
    int dlB = dlA + DPW;
    int dA = node0 + dlA, dB = node0 + dlB;
    int4 qA = make_int4(0, 0, 0, 0), qB = make_int4(0, 0, 0, 0);
    if (dA < NN) qA = *(const int4*)(rs4 + (size_t)4 * dA);
    if (dB < NN) qB = *(const int4*)(rs4 + (size_t)4 * dB);
    int lenA = qA.w - qA.x, lenB = qB.w - qB.x;
    int L = lenA > lenB ? lenA : lenB;
    float4 aA0 = make_float4(0.f, 0.f, 0.f, 0.f);
    float4 aA1 = make_float4(0.f, 0.f, 0.f, 0.f);
    float4 aA2 = make_float4(0.f, 0.f, 0.f, 0.f);
    float4 aB0 = make_float4(0.f, 0.f, 0.f, 0.f);
    float4 aB1 = make_float4(0.f, 0.f, 0.f, 0.f);
    float4 aB2 = make_float4(0.f, 0.f, 0.f, 0.f);
    for (int base = 0; base < L; base += SW) {
      // chunk edge IDs for both dsts: 1 coalesced load each; over-reads land
      // in later runs / zero pad -> always a valid id or 0
      int epvA = ep[qA.x + base + sl];
      int epvB = ep[qB.x + base + sl];
      int pendA = (lenA < base + SW) ? lenA : base + SW;
      int pendB = (lenB < base + SW) ? lenB : base + SW;
      int pend = pendA > pendB ? pendA : pendB;
#pragma unroll 4
      for (int p = base; p < pend; p += EPI) {
        int off = p + es;
        int srcLane = subBase | ((off - base) & (SW - 1));
        int eA = __shfl(epvA, srcLane, 64);
        int eB = __shfl(epvB, srcLane, 64);
        float4 vA = *(const float4*)(x + (size_t)eA * IN + k4 * 4);
        float4 vB = *(const float4*)(x + (size_t)eB * IN + k4 * 4);
        int iA = qA.x + off, iB = qB.x + off;
        bool vlA = off < pendA, vlB = off < pendB;
        float mA0 = (vlA && iA < qA.y) ? 1.f : 0.f;
        float mA1 = (vlA && iA >= qA.y && iA < qA.z) ? 1.f : 0.f;
        float mA2 = (vlA && iA >= qA.z) ? 1.f : 0.f;
        float mB0 = (vlB && iB < qB.y) ? 1.f : 0.f;
        float mB1 = (vlB && iB >= qB.y && iB < qB.z) ? 1.f : 0.f;
        float mB2 = (vlB && iB >= qB.z) ? 1.f : 0.f;
        aA0.x = fmaf(mA0, vA.x, aA0.x); aA0.y = fmaf(mA0, vA.y, aA0.y);
        aA0.z = fmaf(mA0, vA.z, aA0.z); aA0.w = fmaf(mA0, vA.w, aA0.w);
        aB0.x = fmaf(mB0, vB.x, aB0.x); aB0.y = fmaf(mB0, vB.y, aB0.y);
        aB0.z = fmaf(mB0, vB.z, aB0.z); aB0.w = fmaf(mB0, vB.w, aB0.w);
        aA1.x = fmaf(mA1, vA.x, aA1.x); aA1.y = fmaf(mA1, vA.y, aA1.y);
        aA1.z = fmaf(mA1, vA.z, aA1.z); aA1.w = fmaf(mA1, vA.w, aA1.w);
        aB1.x = fmaf(mB1, vB.x, aB1.x); aB1.y = fmaf(mB1, vB.y, aB1.y);
        aB1.z = fmaf(mB1, vB.z, aB1.z); aB1.w = fmaf(mB1, vB.w, aB1.w);
        aA2.x = fmaf(mA2, vA.x, aA2.x); aA2.y = fmaf(mA2, vA.y, aA2.y);
        aA2.z = fmaf(mA2, vA.z, aA2.z); aA2.w = fmaf(mA2, vA.w, aA2.w);
        aB2.x = fmaf(mB2, vB.x, aB2.x); aB2.y = fmaf(mB2, vB.y, aB2.y);
        aB2.z = fmaf(mB2, vB.z, aB2.z); aB2.w = fmaf(mB2, vB.w, aB2.w);
      }
    }
    // interleaved shuffle reduces (two independent chains)
#pragma unroll
    for (int off = LPE; off < SW; off <<= 1) {
      aA0.x += __shfl_xor(aA0.x, off, 64); aB0.x += __shfl_xor(aB0.x, off, 64);
      aA0.y += __shfl_xor(aA0.y, off, 64); aB0.y += __shfl_xor(aB0.y, off, 64);
      aA0.z += __shfl_xor(aA0.z, off, 64); aB0.z += __shfl_xor(aB0.z, off, 64);
      aA0.w += __shfl_xor(aA0.w, off, 64); aB0.w += __shfl_xor(aB0.w, off, 64);
      aA1.x += __shfl_xor(aA1.x, off, 64); aB1.x += __shfl_xor(aB1.x, off, 64);
      aA1.y += __shfl_xor(aA1.y, off, 64); aB1.y += __shfl_xor(aB1.y, off, 64);
      aA1.z += __shfl_xor(aA1.z, off, 64); aB1.z += __shfl_xor(aB1.z, off, 64);
      aA1.w += __shfl_xor(aA1.w, off, 64); aB1.w += __shfl_xor(aB1.w, off, 64);
      aA2.x += __shfl_xor(aA2.x, off, 64); aB2.x += __shfl_xor(aB2.x, off, 64);
      aA2.y += __shfl_xor(aA2.y, off, 64); aB2.y += __shfl_xor(aB2.y, off, 64);
      aA2.z += __shfl_xor(aA2.z, off, 64); aB2.z += __shfl_xor(aB2.z, off, 64);
      aA2.w += __shfl_xor(aA2.w, off, 64); aB2.w += __shfl_xor(aB2.w, off, 64);
    }
    if (es == 0) {
      int r0 = k4 * 4;
      if (dA < NN) {
        float c0 = (float)(qA.y - qA.x > 0 ? qA.y - qA.x : 1);
        float c1 = (float)(qA.z - qA.y > 0 ? qA.z - qA.y : 1);
        float c2 = (float)(qA.w - qA.z > 0 ? qA.w - qA.z : 1);
        smem[0 * IN + r0 + 0][dlA] = aA0.x / c0;
        smem[0 * IN + r0 + 1][dlA] = aA0.y / c0;
        smem[0 * IN + r0 + 2][dlA] = aA0.z / c0;
        smem[0 * IN + r0 + 3][dlA] = aA0.w / c0;
        smem[1 * IN + r0 + 0][dlA] = aA1.x / c1;
        smem[1 * IN + r0 + 1][dlA] = aA1.y / c1;
        smem[1 * IN + r0 + 2][dlA] = aA1.z / c1;
        smem[1 * IN + r0 + 3][dlA] = aA1.w / c1;
        float4 o2;
        o2.x = aA2.x / c2; o2.y = aA2.y / c2;
        o2.z = aA2.z / c2; o2.w = aA2.w / c2;
        *(float4*)(h2 + (size_t)dA * IN + r0) = o2;
      }
      if (dB < NN) {
        float c0 = (float)(qB.y - qB.x > 0 ? qB.y - qB.x : 1);
        float c1 = (float)(qB.z - qB.y > 0 ? qB.z - qB.y : 1);
        float c2 = (float)(qB.w - qB.z > 0 ? qB.w - qB.z : 1);
        smem[0 * IN + r0 + 0][dlB] = aB0.x / c0;
        smem[0 * IN + r0 + 1][dlB] = aB0.y / c0;
        smem[0 * IN + r0 + 2][dlB] = aB0.z / c0;
        smem[0 * IN + r0 + 3][dlB] = aB0.w / c0;
        smem[1 * IN + r0 + 0][dlB] = aB1.x / c1;
        smem[1 * IN + r0 + 1][dlB] = aB1.y / c1;
        smem[1 * IN + r0 + 2][dlB] = aB1.z / c1;
        smem[1 * IN + r0 + 3][dlB] = aB1.w / c1;
        float4 o2;
        o2.x = aB2.x / c2; o2.y = aB2.y / c2;
        o2.z = aB2.z / c2; o2.w = aB2.w / c2;
        *(float4*)(h2 + (size_t)dB * IN + r0) = o2;
      }
    }
  }
  __syncthreads();   // a0/a1 visible in LDS; h2 stores drained

  // ================= Phase B: dense (rotating buffers) =================
  const int n = lane;
  const int j0 = __builtin_amdgcn_readfirstlane(wv * 8);
  constexpr int F4 = IN / 4;
  constexpr int NPF = (64 * F4) / 512;   // prefetch float4 per thread (2 or 1)

  // issue h2 prefetch; latency hides under mm(rel0)+mm(rel1)
  float4 pf[NPF];
  int s_nn[NPF], s_c4[NPF];
#pragma unroll
  for (int u = 0; u < NPF; ++u) {
    int idx = u * 512 + tid;
    s_nn[u] = idx / F4;
    s_c4[u] = idx % F4;
    int node = node0 + s_nn[u];
    pf[u] = make_float4(0.f, 0.f, 0.f, 0.f);
    if (node < NN) pf[u] = *(const float4*)(h2 + (size_t)node * IN + s_c4[u] * 4);
  }

  float acc[8];
#pragma unroll
  for (int j = 0; j < 8; ++j) acc[j] = bias[j0 + j];

  auto mm = [&](const float* __restrict__ W, int row0) {
#pragma unroll 4
    for (int k = 0; k < IN; ++k) {
      float sk = smem[row0 + k][n];
      const float* w = W + (size_t)k * 64 + j0;
#pragma unroll
      for (int j = 0; j < 8; ++j) acc[j] = fmaf(sk, w[j], acc[j]);
    }
  };

  mm(rel, 0);                             // mean0 @ rel0   (rows [0,IN))
  mm(rel + (size_t)IN * 64, IN);          // mean1 @ rel1   (rows [IN,2IN))
  __syncthreads();                        // rows[0,IN) free

  // commit mean2 over mean0's rows; then reuse pf for the x prefetch
#pragma unroll
  for (int u = 0; u < NPF; ++u) {
    int c4 = s_c4[u], nn = s_nn[u];
    smem[c4 * 4 + 0][nn] = pf[u].x;
    smem[c4 * 4 + 1][nn] = pf[u].y;
    smem[c4 * 4 + 2][nn] = pf[u].z;
    smem[c4 * 4 + 3][nn] = pf[u].w;
  }
#pragma unroll
  for (int u = 0; u < NPF; ++u) {
    int node = node0 + s_nn[u];
    pf[u] = make_float4(0.f, 0.f, 0.f, 0.f);
    if (node < NN) pf[u] = *(const float4*)(x + (size_t)node * IN + s_c4[u] * 4);
  }
  __syncthreads();
  mm(rel + (size_t)2 * IN * 64, 0);       // mean2 @ rel2   (rows [0,IN))
  __syncthreads();                        // rows[IN,2IN) free

  // commit x over mean1's rows
#pragma unroll
  for (int u = 0; u < NPF; ++u) {
    int c4 = s_c4[u], nn = s_nn[u];
    smem[IN + c4 * 4 + 0][nn] = pf[u].x;
    smem[IN + c4 * 4 + 1][nn] = pf[u].y;
    smem[IN + c4 * 4 + 2][nn] = pf[u].z;
    smem[IN + c4 * 4 + 3][nn] = pf[u].w;
  }
  __syncthreads();
  mm(root, IN);                           // x @ root       (rows [IN,2IN))

  int node = node0 + n;
  if (node < NN) {
    float4* o = (float4*)(y + (size_t)node * 64 + j0);
    float4 v;
    v.x = fmaxf(acc[0], 0.f); v.y = fmaxf(acc[1], 0.f);
    v.z = fmaxf(acc[2], 0.f); v.w = fmaxf(acc[3], 0.f);
    o[0] = v;
    v.x = fmaxf(acc[4], 0.f); v.y = fmaxf(acc[5], 0.f);
    v.z = fmaxf(acc[6], 0.f); v.w = fmaxf(acc[7], 0.f);
    o[1] = v;
  }
}

// ---------- mean pool over sorted batch ids (run-length reduce, then atomic) ----------
__global__ __launch_bounds__(256) void k_pool(
    const float* __restrict__ x3, const int* __restrict__ batch,
    float* __restrict__ pooled, float* __restrict__ gcnt)
{
  int gwave = (blockIdx.x * 256 + threadIdx.x) >> 6;
  int lane = threadIdx.x & 63;
  int n0 = gwave * 64;
  if (n0 >= NN) return;
  int n1 = n0 + 64 < NN ? n0 + 64 : NN;
  int gcur = batch[n0];
  float acc = 0.f;
  int run = 0;
  for (int n = n0; n < n1; ++n) {
    int g = batch[n];
    if (g != gcur) {
      atomicAdd(&pooled[gcur * 64 + lane], acc);
      if (lane == 0) atomicAdd(&gcnt[gcur], (float)run);
      acc = 0.f; run = 0; gcur = g;
    }
    acc += x3[(size_t)n * 64 + lane];
    ++run;
  }
  atomicAdd(&pooled[gcur * 64 + lane], acc);
  if (lane == 0) atomicAdd(&gcnt[gcur], (float)run);
}

// ---------- classifier ----------
__global__ __launch_bounds__(256) void k_cls(
    const float* __restrict__ pooled, const float* __restrict__ gcnt,
    const float* __restrict__ cw, const float* __restrict__ cb, float* __restrict__ out)
{
  int t = blockIdx.x * 256 + threadIdx.x;
  if (t >= NG * 10) return;
  int g = t / 10, c = t % 10;
  float cf = fmaxf(gcnt[g], 1.f);
  float acc = cb[c];
#pragma unroll 8
  for (int k = 0; k < 64; ++k)
    acc += (pooled[g * 64 + k] / cf) * cw[k * 10 + c];
  out[t] = acc;
}

extern "C" void kernel_launch(void* const* d_in, const int* in_sizes, int n_in,
                              void* d_out, int out_size, void* d_ws, size_t ws_size,
                              hipStream_t stream)
{
  const int* nf = (const int*)d_in[0];
  const int* ei = (const int*)d_in[1];
  const int* et = (const int*)d_in[2];
  const int* batch = (const int*)d_in[3];
  const float* semb = (const float*)d_in[4];
  const float* cemb = (const float*)d_in[5];
  const float* pw = (const float*)d_in[6];
  const float* pb = (const float*)d_in[7];
  const float* root1 = (const float*)d_in[8];
  const float* rel1 = (const float*)d_in[9];
  const float* bias1 = (const float*)d_in[10];
  const float* root2 = (const float*)d_in[11];
  const float* rel2 = (const float*)d_in[12];
  const float* bias2 = (const float*)d_in[13];
  const float* cw = (const float*)d_in[14];
  const float* cb = (const float*)d_in[15];
  float* out = (float*)d_out;

  char* ws = (char*)d_ws;
  size_t off = 0;
  auto alloc = [&](size_t bytes) {
    char* p = ws + off;
    off += (bytes + 255) & ~(size_t)255;
    return p;
  };
  int* bkt_cur = (int*)alloc((size_t)NB * 4);
  int* rs4 = (int*)alloc((size_t)NN * 4 * 4);             // per-node run bounds (int4)
  int* ep = (int*)alloc(((size_t)NB * CAPB + 64) * 4);    // padded-bucket, type-sorted
  int* binned = (int*)alloc((size_t)NB * CAPB * 4);       // binning scratch
  float* h2 = (float*)alloc((size_t)NN * 64 * 4);         // mean2 spill (phase B reload)
  float* xA = (float*)alloc((size_t)NN * 64 * 4);         // x2
  float* xB = (float*)alloc((size_t)NN * 64 * 4);         // x1 ([N,32]) then x3
  float* pooled = (float*)alloc((size_t)NG * 64 * 4);
  float* gcnt = (float*)alloc((size_t)NG * 4);
  (void)ws_size; (void)in_sizes; (void)n_in; (void)out_size;

  hipMemsetAsync(bkt_cur, 0, (size_t)NB * 4, stream);
  // zero ep so gap/pad slots read as src=0 (masked by w=0 in the gather)
  hipMemsetAsync(ep, 0, ((size_t)NB * CAPB + 64) * 4, stream);
  k_embed<<<(NN + 255) / 256, 256, 0, stream>>>(nf, semb, cemb, pw, pb, xB);

  // CSR build: padded-bucket counting sort (no count/scan pass)
  kA_scatter<<<NAB, 256, 0, stream>>>(ei, et, bkt_cur, binned);
  kB_build<<<NB, 512, 0, stream>>>(bkt_cur, binned, rs4, ep);

  int fgrid = (NN + 63) / 64;  // 1563 blocks, 64 dsts each

  // layer 1: x1 (xB) -> x2 (xA);  layer 2: x2 (xA) -> x3 (xB)
  k_fused<32><<<fgrid, 512, 0, stream>>>(xB, rs4, ep, root1, rel1, bias1, h2, xA);
  k_fused<64><<<fgrid, 512, 0, stream>>>(xA, rs4, ep, root2, rel2, bias2, h2, xB);

  hipMemsetAsync(pooled, 0, (size_t)NG * 64 * 4, stream);
  hipMemsetAsync(gcnt, 0, (size_t)NG * 4, stream);
  int nwaves = (NN + 63) / 64;
  k_pool<<<(nwaves + 3) / 4, 256, 0, stream>>>(xB, batch, pooled, gcnt);
  k_cls<<<(NG * 10 + 255) / 256, 256, 0, stream>>>(pooled, gcnt, cw, cb, out);
}

// Round 18
// 267.161 us; speedup vs baseline: 1.2158x; 1.2158x over previous
//
#include <hip/hip_runtime.h>

#define NN 100000
#define NE 1600000
#define NG 512

#define BSH 9                         // bucket = dst >> 9 (512 nodes/bucket)
#define NB 196                        // ceil(NN / 512)
#define EPB 8192                      // edges per block in phase A
#define NAB ((NE + EPB - 1) / EPB)    // 196 phase-A blocks
#define CAPB 9216                     // fixed bucket capacity (mean 8192, sigma~90)
#define CAP 9216                      // LDS staging capacity in kB_build

// ---------- embedding lookup + pre-linear + relu: x1[N,32] ----------
__global__ __launch_bounds__(256) void k_embed(
    const int* __restrict__ nf, const float* __restrict__ semb,
    const float* __restrict__ cemb, const float* __restrict__ pw,
    const float* __restrict__ pb, float* __restrict__ x1)
{
  int gid = blockIdx.x * 256 + threadIdx.x;
  bool valid = gid < NN;
  int i = valid ? gid : NN - 1;
  int sf = nf[2 * i], cf = nf[2 * i + 1];
  float x0[16];
#pragma unroll
  for (int k = 0; k < 8; ++k) x0[k] = semb[sf * 8 + k];
#pragma unroll
  for (int k = 0; k < 8; ++k) x0[8 + k] = cemb[cf * 8 + k];
  float acc[32];
#pragma unroll
  for (int j = 0; j < 32; ++j) acc[j] = pb[j];
#pragma unroll
  for (int k = 0; k < 16; ++k) {
    float xv = x0[k];
#pragma unroll
    for (int j = 0; j < 32; ++j) acc[j] += xv * pw[k * 32 + j];
  }
  if (valid) {
    float4* o = (float4*)(x1 + (size_t)i * 32);
#pragma unroll
    for (int j4 = 0; j4 < 8; ++j4) {
      float4 v;
      v.x = fmaxf(acc[4 * j4 + 0], 0.f);
      v.y = fmaxf(acc[4 * j4 + 1], 0.f);
      v.z = fmaxf(acc[4 * j4 + 2], 0.f);
      v.w = fmaxf(acc[4 * j4 + 3], 0.f);
      o[j4] = v;
    }
  }
}

// ---------- CSR build: padded-bucket counting sort ----------
// pack: src(0-16) | type(17-18) | dst&511 (19-27)
__global__ __launch_bounds__(256) void kA_scatter(
    const int* __restrict__ ei, const int* __restrict__ et,
    int* __restrict__ bkt_cur, int* __restrict__ binned)
{
  __shared__ int packA[EPB];
  __shared__ unsigned char bktA[EPB];
  __shared__ int lh[NB], grun[NB], lcur[NB];
  for (int b = threadIdx.x; b < NB; b += 256) { lh[b] = 0; lcur[b] = 0; }
  __syncthreads();
  int base = blockIdx.x * EPB;
#pragma unroll
  for (int i = 0; i < EPB / 256; ++i) {
    int p = i * 256 + threadIdx.x;
    int e = base + p;
    if (e < NE) {
      int src = ei[e], dst = ei[NE + e], ty = et[e];
      int b = dst >> BSH;
      packA[p] = src | (ty << 17) | ((dst & 511) << 19);
      bktA[p] = (unsigned char)b;
      atomicAdd(&lh[b], 1);
    } else {
      bktA[p] = 255;
    }
  }
  __syncthreads();
  for (int b = threadIdx.x; b < NB; b += 256)
    grun[b] = lh[b] ? atomicAdd(&bkt_cur[b], lh[b]) : 0;
  __syncthreads();
#pragma unroll
  for (int i = 0; i < EPB / 256; ++i) {
    int p = i * 256 + threadIdx.x;
    int b = bktA[p];
    if (b != 255) {
      int off = grun[b] + atomicAdd(&lcur[b], 1);
      if (off < CAPB) binned[b * CAPB + off] = packA[p];
    }
  }
}

// Phase B: one workgroup per bucket; key = dst_local*3 + type -> per-node
// edge list sorted by relation; rs4[d*4+r] run starts, rs4[d*4+3] run end.
__global__ __launch_bounds__(512) void kB_build(
    const int* __restrict__ bkt_cur, const int* __restrict__ binned,
    int* __restrict__ rs4, int* __restrict__ ep)
{
  __shared__ int stage[CAP];
  __shared__ int ldeg3[1536], lrs3[1536], lcur3[1536];
  __shared__ int sm[2][512];
  int b = blockIdx.x;
  int t = threadIdx.x;
  int p0 = b * CAPB;
  int cnt = bkt_cur[b];
  if (cnt > CAPB) cnt = CAPB;
  int nodes0 = b << BSH;
  int nnodes = NN - nodes0 < 512 ? NN - nodes0 : 512;
  ldeg3[t] = 0; ldeg3[t + 512] = 0; ldeg3[t + 1024] = 0;
  lcur3[t] = 0; lcur3[t + 512] = 0; lcur3[t + 1024] = 0;
  __syncthreads();
  for (int p = t; p < cnt; p += 512) {
    int pk = binned[p0 + p];
    if (p < CAP) stage[p] = pk;
    int key = ((pk >> 19) & 511) * 3 + ((pk >> 17) & 3);
    atomicAdd(&ldeg3[key], 1);
  }
  __syncthreads();
  int s0 = ldeg3[3 * t], s1 = ldeg3[3 * t + 1], s2 = ldeg3[3 * t + 2];
  int tot = s0 + s1 + s2;
  sm[0][t] = tot;
  __syncthreads();
  int cur = 0;
#pragma unroll
  for (int off = 1; off < 512; off <<= 1) {
    int add = (t >= off) ? sm[cur][t - off] : 0;
    sm[cur ^ 1][t] = sm[cur][t] + add;
    __syncthreads();
    cur ^= 1;
  }
  int ex = sm[cur][t] - tot;  // exclusive
  int r0 = p0 + ex, r1 = r0 + s0, r2 = r1 + s1;
  lrs3[3 * t] = r0;
  lrs3[3 * t + 1] = r1;
  lrs3[3 * t + 2] = r2;
  if (t < nnodes) {
    *(int4*)(rs4 + (size_t)4 * (nodes0 + t)) = make_int4(r0, r1, r2, r2 + s2);
  }
  __syncthreads();
  for (int p = t; p < cnt; p += 512) {
    int pk = (p < CAP) ? stage[p] : binned[p0 + p];
    int key = ((pk >> 19) & 511) * 3 + ((pk >> 17) & 3);
    int off = atomicAdd(&lcur3[key], 1);
    ep[lrs3[key] + off] = pk & 0x1FFFF;  // src only
  }
}

// ---------- FUSED agg + dense: y[d] = relu(x[d]@root + b + sum_r mean_r@rel_r) ----
// R16 (measured best: occupancy fix, 2-stream LDS + h2 spill) with ONE
// change: phase A inner unroll 4 -> 8. R17's 2-dst pairing spilled (12 live
// accumulators > 64-VGPR budget at 8 waves/SIMD -> 120MB scratch traffic);
// unroll deepening gets the same extra MLP (8 gathers in flight) while only
// extending LOAD-TEMPORARY live ranges, not accumulator count: ~50-56 VGPR.
// IN=32's chunk (8 iterations) becomes fully unrolled.
template <int IN>
__global__ __launch_bounds__(512, 8) void k_fused(
    const float* __restrict__ x, const int* __restrict__ rs4,
    const int* __restrict__ ep, const float* __restrict__ root,
    const float* __restrict__ rel, const float* __restrict__ bias,
    float* __restrict__ h2, float* __restrict__ y)
{
  __shared__ float smem[2 * IN][65];
  const int tid = threadIdx.x;
  const int node0 = blockIdx.x * 64;
  const int wv = tid >> 6;
  const int lane = tid & 63;

  constexpr int LPE = IN / 4;              // lanes per edge-row (16 or 8)
  constexpr int DPW = (IN == 32) ? 2 : 1;  // dsts per wave-iteration
  constexpr int SW = 64 / DPW;             // lanes per dst (64 or 32)
  constexpr int EPI = SW / LPE;            // 4 edges per iteration
  const int sub = (IN == 64) ? 0 : (lane >> 5);
  const int sl = lane & (SW - 1);
  const int k4 = sl % LPE;                 // float4 column within row
  const int es = sl / LPE;                 // edge slot 0..3
  const int subBase = lane & ~(SW - 1);

  // ================= Phase A: gather means; a0/a1 -> LDS, a2 -> global =====
  for (int it = 0; it < 8 / DPW; ++it) {
    int dl = wv * 8 + it * DPW + sub;      // local dst 0..63 (exclusive per wave)
    int d = node0 + dl;
    int4 q = make_int4(0, 0, 0, 0);
    if (d < NN) q = *(const int4*)(rs4 + (size_t)4 * d);
    const int q0 = q.x, q1 = q.y, q2 = q.z, q3 = q.w;
    float4 a0 = make_float4(0.f, 0.f, 0.f, 0.f);
    float4 a1 = make_float4(0.f, 0.f, 0.f, 0.f);
    float4 a2 = make_float4(0.f, 0.f, 0.f, 0.f);
    for (int base = q0; base < q3; base += SW) {
      int epv = ep[base + sl];             // whole chunk's edge IDs, 1 load
      int pend = (base + SW < q3) ? base + SW : q3;
#pragma unroll 8
      for (int p = base; p < pend; p += EPI) {
        int idx = p + es;
        bool val = idx < pend;
        int srcLane = subBase | ((idx - base) & (SW - 1));
        int e = __shfl(epv, srcLane, 64);
        float4 v = *(const float4*)(x + (size_t)e * IN + k4 * 4);
        float m0 = (val && idx < q1) ? 1.f : 0.f;
        float m1 = (val && idx >= q1 && idx < q2) ? 1.f : 0.f;
        float m2 = (val && idx >= q2) ? 1.f : 0.f;
        a0.x = fmaf(m0, v.x, a0.x); a0.y = fmaf(m0, v.y, a0.y);
        a0.z = fmaf(m0, v.z, a0.z); a0.w = fmaf(m0, v.w, a0.w);
        a1.x = fmaf(m1, v.x, a1.x); a1.y = fmaf(m1, v.y, a1.y);
        a1.z = fmaf(m1, v.z, a1.z); a1.w = fmaf(m1, v.w, a1.w);
        a2.x = fmaf(m2, v.x, a2.x); a2.y = fmaf(m2, v.y, a2.y);
        a2.z = fmaf(m2, v.z, a2.z); a2.w = fmaf(m2, v.w, a2.w);
      }
    }
#pragma unroll
    for (int off = LPE; off < SW; off <<= 1) {
      a0.x += __shfl_xor(a0.x, off, 64); a0.y += __shfl_xor(a0.y, off, 64);
      a0.z += __shfl_xor(a0.z, off, 64); a0.w += __shfl_xor(a0.w, off, 64);
      a1.x += __shfl_xor(a1.x, off, 64); a1.y += __shfl_xor(a1.y, off, 64);
      a1.z += __shfl_xor(a1.z, off, 64); a1.w += __shfl_xor(a1.w, off, 64);
      a2.x += __shfl_xor(a2.x, off, 64); a2.y += __shfl_xor(a2.y, off, 64);
      a2.z += __shfl_xor(a2.z, off, 64); a2.w += __shfl_xor(a2.w, off, 64);
    }
    if (es == 0 && d < NN) {
      float c0 = (float)(q1 - q0 > 0 ? q1 - q0 : 1);
      float c1 = (float)(q2 - q1 > 0 ? q2 - q1 : 1);
      float c2 = (float)(q3 - q2 > 0 ? q3 - q2 : 1);
      int r0 = k4 * 4;
      smem[0 * IN + r0 + 0][dl] = a0.x / c0;
      smem[0 * IN + r0 + 1][dl] = a0.y / c0;
      smem[0 * IN + r0 + 2][dl] = a0.z / c0;
      smem[0 * IN + r0 + 3][dl] = a0.w / c0;
      smem[1 * IN + r0 + 0][dl] = a1.x / c1;
      smem[1 * IN + r0 + 1][dl] = a1.y / c1;
      smem[1 * IN + r0 + 2][dl] = a1.z / c1;
      smem[1 * IN + r0 + 3][dl] = a1.w / c1;
      float4 o2;
      o2.x = a2.x / c2; o2.y = a2.y / c2; o2.z = a2.z / c2; o2.w = a2.w / c2;
      *(float4*)(h2 + (size_t)d * IN + r0) = o2;   // coalesced 256B per dst
    }
  }
  __syncthreads();   // a0/a1 visible in LDS; h2 stores drained (vmcnt in barrier)

  // ================= Phase B: dense (rotating buffers) =================
  const int n = lane;
  const int j0 = __builtin_amdgcn_readfirstlane(wv * 8);
  constexpr int F4 = IN / 4;
  constexpr int NPF = (64 * F4) / 512;   // prefetch float4 per thread (2 or 1)

  // issue h2 prefetch; latency hides under mm(rel0)+mm(rel1)
  float4 pf[NPF];
  int s_nn[NPF], s_c4[NPF];
#pragma unroll
  for (int u = 0; u < NPF; ++u) {
    int idx = u * 512 + tid;
    s_nn[u] = idx / F4;
    s_c4[u] = idx % F4;
    int node = node0 + s_nn[u];
    pf[u] = make_float4(0.f, 0.f, 0.f, 0.f);
    if (node < NN) pf[u] = *(const float4*)(h2 + (size_t)node * IN + s_c4[u] * 4);
  }

  float acc[8];
#pragma unroll
  for (int j = 0; j < 8; ++j) acc[j] = bias[j0 + j];

  auto mm = [&](const float* __restrict__ W, int row0) {
#pragma unroll 4
    for (int k = 0; k < IN; ++k) {
      float sk = smem[row0 + k][n];
      const float* w = W + (size_t)k * 64 + j0;
#pragma unroll
      for (int j = 0; j < 8; ++j) acc[j] = fmaf(sk, w[j], acc[j]);
    }
  };

  mm(rel, 0);                             // mean0 @ rel0   (rows [0,IN))
  mm(rel + (size_t)IN * 64, IN);          // mean1 @ rel1   (rows [IN,2IN))
  __syncthreads();                        // rows[0,IN) free

  // commit mean2 over mean0's rows; then reuse pf for the x prefetch
#pragma unroll
  for (int u = 0; u < NPF; ++u) {
    int c4 = s_c4[u], nn = s_nn[u];
    smem[c4 * 4 + 0][nn] = pf[u].x;
    smem[c4 * 4 + 1][nn] = pf[u].y;
    smem[c4 * 4 + 2][nn] = pf[u].z;
    smem[c4 * 4 + 3][nn] = pf[u].w;
  }
#pragma unroll
  for (int u = 0; u < NPF; ++u) {
    int node = node0 + s_nn[u];
    pf[u] = make_float4(0.f, 0.f, 0.f, 0.f);
    if (node < NN) pf[u] = *(const float4*)(x + (size_t)node * IN + s_c4[u] * 4);
  }
  __syncthreads();
  mm(rel + (size_t)2 * IN * 64, 0);       // mean2 @ rel2   (rows [0,IN))
  __syncthreads();                        // rows[IN,2IN) free

  // commit x over mean1's rows
#pragma unroll
  for (int u = 0; u < NPF; ++u) {
    int c4 = s_c4[u], nn = s_nn[u];
    smem[IN + c4 * 4 + 0][nn] = pf[u].x;
    smem[IN + c4 * 4 + 1][nn] = pf[u].y;
    smem[IN + c4 * 4 + 2][nn] = pf[u].z;
    smem[IN + c4 * 4 + 3][nn] = pf[u].w;
  }
  __syncthreads();
  mm(root, IN);                           // x @ root       (rows [IN,2IN))

  int node = node0 + n;
  if (node < NN) {
    float4* o = (float4*)(y + (size_t)node * 64 + j0);
    float4 v;
    v.x = fmaxf(acc[0], 0.f); v.y = fmaxf(acc[1], 0.f);
    v.z = fmaxf(acc[2], 0.f); v.w = fmaxf(acc[3], 0.f);
    o[0] = v;
    v.x = fmaxf(acc[4], 0.f); v.y = fmaxf(acc[5], 0.f);
    v.z = fmaxf(acc[6], 0.f); v.w = fmaxf(acc[7], 0.f);
    o[1] = v;
  }
}

// ---------- mean pool over sorted batch ids (run-length reduce, then atomic) ----------
__global__ __launch_bounds__(256) void k_pool(
    const float* __restrict__ x3, const int* __restrict__ batch,
    float* __restrict__ pooled, float* __restrict__ gcnt)
{
  int gwave = (blockIdx.x * 256 + threadIdx.x) >> 6;
  int lane = threadIdx.x & 63;
  int n0 = gwave * 64;
  if (n0 >= NN) return;
  int n1 = n0 + 64 < NN ? n0 + 64 : NN;
  int gcur = batch[n0];
  float acc = 0.f;
  int run = 0;
  for (int n = n0; n < n1; ++n) {
    int g = batch[n];
    if (g != gcur) {
      atomicAdd(&pooled[gcur * 64 + lane], acc);
      if (lane == 0) atomicAdd(&gcnt[gcur], (float)run);
      acc = 0.f; run = 0; gcur = g;
    }
    acc += x3[(size_t)n * 64 + lane];
    ++run;
  }
  atomicAdd(&pooled[gcur * 64 + lane], acc);
  if (lane == 0) atomicAdd(&gcnt[gcur], (float)run);
}

// ---------- classifier ----------
__global__ __launch_bounds__(256) void k_cls(
    const float* __restrict__ pooled, const float* __restrict__ gcnt,
    const float* __restrict__ cw, const float* __restrict__ cb, float* __restrict__ out)
{
  int t = blockIdx.x * 256 + threadIdx.x;
  if (t >= NG * 10) return;
  int g = t / 10, c = t % 10;
  float cf = fmaxf(gcnt[g], 1.f);
  float acc = cb[c];
#pragma unroll 8
  for (int k = 0; k < 64; ++k)
    acc += (pooled[g * 64 + k] / cf) * cw[k * 10 + c];
  out[t] = acc;
}

extern "C" void kernel_launch(void* const* d_in, const int* in_sizes, int n_in,
                              void* d_out, int out_size, void* d_ws, size_t ws_size,
                              hipStream_t stream)
{
  const int* nf = (const int*)d_in[0];
  const int* ei = (const int*)d_in[1];
  const int* et = (const int*)d_in[2];
  const int* batch = (const int*)d_in[3];
  const float* semb = (const float*)d_in[4];
  const float* cemb = (const float*)d_in[5];
  const float* pw = (const float*)d_in[6];
  const float* pb = (const float*)d_in[7];
  const float* root1 = (const float*)d_in[8];
  const float* rel1 = (const float*)d_in[9];
  const float* bias1 = (const float*)d_in[10];
  const float* root2 = (const float*)d_in[11];
  const float* rel2 = (const float*)d_in[12];
  const float* bias2 = (const float*)d_in[13];
  const float* cw = (const float*)d_in[14];
  const float* cb = (const float*)d_in[15];
  float* out = (float*)d_out;

  char* ws = (char*)d_ws;
  size_t off = 0;
  auto alloc = [&](size_t bytes) {
    char* p = ws + off;
    off += (bytes + 255) & ~(size_t)255;
    return p;
  };
  int* bkt_cur = (int*)alloc((size_t)NB * 4);
  int* rs4 = (int*)alloc((size_t)NN * 4 * 4);             // per-node run bounds (int4)
  int* ep = (int*)alloc(((size_t)NB * CAPB + 64) * 4);    // padded-bucket, type-sorted
  int* binned = (int*)alloc((size_t)NB * CAPB * 4);       // binning scratch
  float* h2 = (float*)alloc((size_t)NN * 64 * 4);         // mean2 spill (phase B reload)
  float* xA = (float*)alloc((size_t)NN * 64 * 4);         // x2
  float* xB = (float*)alloc((size_t)NN * 64 * 4);         // x1 ([N,32]) then x3
  float* pooled = (float*)alloc((size_t)NG * 64 * 4);
  float* gcnt = (float*)alloc((size_t)NG * 4);
  (void)ws_size; (void)in_sizes; (void)n_in; (void)out_size;

  hipMemsetAsync(bkt_cur, 0, (size_t)NB * 4, stream);
  // zero ep so gap/pad slots read as src=0 (masked by w=0 in the gather)
  hipMemsetAsync(ep, 0, ((size_t)NB * CAPB + 64) * 4, stream);
  k_embed<<<(NN + 255) / 256, 256, 0, stream>>>(nf, semb, cemb, pw, pb, xB);

  // CSR build: padded-bucket counting sort (no count/scan pass)
  kA_scatter<<<NAB, 256, 0, stream>>>(ei, et, bkt_cur, binned);
  kB_build<<<NB, 512, 0, stream>>>(bkt_cur, binned, rs4, ep);

  int fgrid = (NN + 63) / 64;  // 1563 blocks, 64 dsts each

  // layer 1: x1 (xB) -> x2 (xA);  layer 2: x2 (xA) -> x3 (xB)
  k_fused<32><<<fgrid, 512, 0, stream>>>(xB, rs4, ep, root1, rel1, bias1, h2, xA);
  k_fused<64><<<fgrid, 512, 0, stream>>>(xA, rs4, ep, root2, rel2, bias2, h2, xB);

  hipMemsetAsync(pooled, 0, (size_t)NG * 64 * 4, stream);
  hipMemsetAsync(gcnt, 0, (size_t)NG * 4, stream);
  int nwaves = (NN + 63) / 64;
  k_pool<<<(nwaves + 3) / 4, 256, 0, stream>>>(xB, batch, pooled, gcnt);
  k_cls<<<(NG * 10 + 255) / 256, 256, 0, stream>>>(pooled, gcnt, cw, cb, out);
}

// Round 19
// 266.311 us; speedup vs baseline: 1.2197x; 1.0032x over previous
//
#include <hip/hip_runtime.h>

#define NN 100000
#define NE 1600000
#define NG 512

#define BSH 9                         // bucket = dst >> 9 (512 nodes/bucket)
#define NB 196                        // ceil(NN / 512)
#define EPB 8192                      // edges per block in phase A
#define NAB ((NE + EPB - 1) / EPB)    // 196 phase-A blocks
#define CAPB 9216                     // fixed bucket capacity (mean 8192, sigma~90)
#define CAP 9216                      // LDS staging capacity in kB_build

// ---------- embedding lookup + pre-linear + relu: x1[N,32] ----------
__global__ __launch_bounds__(256) void k_embed(
    const int* __restrict__ nf, const float* __restrict__ semb,
    const float* __restrict__ cemb, const float* __restrict__ pw,
    const float* __restrict__ pb, float* __restrict__ x1)
{
  int gid = blockIdx.x * 256 + threadIdx.x;
  bool valid = gid < NN;
  int i = valid ? gid : NN - 1;
  int sf = nf[2 * i], cf = nf[2 * i + 1];
  float x0[16];
#pragma unroll
  for (int k = 0; k < 8; ++k) x0[k] = semb[sf * 8 + k];
#pragma unroll
  for (int k = 0; k < 8; ++k) x0[8 + k] = cemb[cf * 8 + k];
  float acc[32];
#pragma unroll
  for (int j = 0; j < 32; ++j) acc[j] = pb[j];
#pragma unroll
  for (int k = 0; k < 16; ++k) {
    float xv = x0[k];
#pragma unroll
    for (int j = 0; j < 32; ++j) acc[j] += xv * pw[k * 32 + j];
  }
  if (valid) {
    float4* o = (float4*)(x1 + (size_t)i * 32);
#pragma unroll
    for (int j4 = 0; j4 < 8; ++j4) {
      float4 v;
      v.x = fmaxf(acc[4 * j4 + 0], 0.f);
      v.y = fmaxf(acc[4 * j4 + 1], 0.f);
      v.z = fmaxf(acc[4 * j4 + 2], 0.f);
      v.w = fmaxf(acc[4 * j4 + 3], 0.f);
      o[j4] = v;
    }
  }
}

// ---------- CSR build: padded-bucket counting sort ----------
// pack: src(0-16) | type(17-18) | dst&511 (19-27)
__global__ __launch_bounds__(256) void kA_scatter(
    const int* __restrict__ ei, const int* __restrict__ et,
    int* __restrict__ bkt_cur, int* __restrict__ binned)
{
  __shared__ int packA[EPB];
  __shared__ unsigned char bktA[EPB];
  __shared__ int lh[NB], grun[NB], lcur[NB];
  for (int b = threadIdx.x; b < NB; b += 256) { lh[b] = 0; lcur[b] = 0; }
  __syncthreads();
  int base = blockIdx.x * EPB;
#pragma unroll
  for (int i = 0; i < EPB / 256; ++i) {
    int p = i * 256 + threadIdx.x;
    int e = base + p;
    if (e < NE) {
      int src = ei[e], dst = ei[NE + e], ty = et[e];
      int b = dst >> BSH;
      packA[p] = src | (ty << 17) | ((dst & 511) << 19);
      bktA[p] = (unsigned char)b;
      atomicAdd(&lh[b], 1);
    } else {
      bktA[p] = 255;
    }
  }
  __syncthreads();
  for (int b = threadIdx.x; b < NB; b += 256)
    grun[b] = lh[b] ? atomicAdd(&bkt_cur[b], lh[b]) : 0;
  __syncthreads();
#pragma unroll
  for (int i = 0; i < EPB / 256; ++i) {
    int p = i * 256 + threadIdx.x;
    int b = bktA[p];
    if (b != 255) {
      int off = grun[b] + atomicAdd(&lcur[b], 1);
      if (off < CAPB) binned[b * CAPB + off] = packA[p];
    }
  }
}

// Phase B: one workgroup per bucket; key = dst_local*3 + type -> per-node
// edge list sorted by relation; rs4[d*4+r] run starts, rs4[d*4+3] run end.
__global__ __launch_bounds__(512) void kB_build(
    const int* __restrict__ bkt_cur, const int* __restrict__ binned,
    int* __restrict__ rs4, int* __restrict__ ep)
{
  __shared__ int stage[CAP];
  __shared__ int ldeg3[1536], lrs3[1536], lcur3[1536];
  __shared__ int sm[2][512];
  int b = blockIdx.x;
  int t = threadIdx.x;
  int p0 = b * CAPB;
  int cnt = bkt_cur[b];
  if (cnt > CAPB) cnt = CAPB;
  int nodes0 = b << BSH;
  int nnodes = NN - nodes0 < 512 ? NN - nodes0 : 512;
  ldeg3[t] = 0; ldeg3[t + 512] = 0; ldeg3[t + 1024] = 0;
  lcur3[t] = 0; lcur3[t + 512] = 0; lcur3[t + 1024] = 0;
  __syncthreads();
  for (int p = t; p < cnt; p += 512) {
    int pk = binned[p0 + p];
    if (p < CAP) stage[p] = pk;
    int key = ((pk >> 19) & 511) * 3 + ((pk >> 17) & 3);
    atomicAdd(&ldeg3[key], 1);
  }
  __syncthreads();
  int s0 = ldeg3[3 * t], s1 = ldeg3[3 * t + 1], s2 = ldeg3[3 * t + 2];
  int tot = s0 + s1 + s2;
  sm[0][t] = tot;
  __syncthreads();
  int cur = 0;
#pragma unroll
  for (int off = 1; off < 512; off <<= 1) {
    int add = (t >= off) ? sm[cur][t - off] : 0;
    sm[cur ^ 1][t] = sm[cur][t] + add;
    __syncthreads();
    cur ^= 1;
  }
  int ex = sm[cur][t] - tot;  // exclusive
  int r0 = p0 + ex, r1 = r0 + s0, r2 = r1 + s1;
  lrs3[3 * t] = r0;
  lrs3[3 * t + 1] = r1;
  lrs3[3 * t + 2] = r2;
  if (t < nnodes) {
    *(int4*)(rs4 + (size_t)4 * (nodes0 + t)) = make_int4(r0, r1, r2, r2 + s2);
  }
  __syncthreads();
  for (int p = t; p < cnt; p += 512) {
    int pk = (p < CAP) ? stage[p] : binned[p0 + p];
    int key = ((pk >> 19) & 511) * 3 + ((pk >> 17) & 3);
    int off = atomicAdd(&lcur3[key], 1);
    ep[lrs3[key] + off] = pk & 0x1FFFF;  // src only
  }
}

// ---------- FUSED agg + dense: y[d] = relu(x[d]@root + b + sum_r mean_r@rel_r) ----
// IN=64: R16/R18 measured-best (2-stream LDS 33.3KB -> 4 blocks/CU, mean2
// spilled to global h2, rotating phase-B buffers).
// IN=32 (R19): 3 streams fit at 24.96KB with the SAME 4-blocks/CU occupancy
// (wave cap binds, not LDS) -> keep mean2 in LDS, delete its h2 round-trip
// (12.8MB write + 12.8MB read) and two phase-B barriers. if constexpr split;
// the IN=64 path is untouched.
template <int IN>
__global__ __launch_bounds__(512, 8) void k_fused(
    const float* __restrict__ x, const int* __restrict__ rs4,
    const int* __restrict__ ep, const float* __restrict__ root,
    const float* __restrict__ rel, const float* __restrict__ bias,
    float* __restrict__ h2, float* __restrict__ y)
{
  constexpr int NSTREAM = (IN == 64) ? 2 : 3;
  __shared__ float smem[NSTREAM * IN][65];
  const int tid = threadIdx.x;
  const int node0 = blockIdx.x * 64;
  const int wv = tid >> 6;
  const int lane = tid & 63;

  constexpr int LPE = IN / 4;              // lanes per edge-row (16 or 8)
  constexpr int DPW = (IN == 32) ? 2 : 1;  // dsts per wave-iteration
  constexpr int SW = 64 / DPW;             // lanes per dst (64 or 32)
  constexpr int EPI = SW / LPE;            // 4 edges per iteration
  const int sub = (IN == 64) ? 0 : (lane >> 5);
  const int sl = lane & (SW - 1);
  const int k4 = sl % LPE;                 // float4 column within row
  const int es = sl / LPE;                 // edge slot 0..3
  const int subBase = lane & ~(SW - 1);

  // ================= Phase A: gather means =====
  for (int it = 0; it < 8 / DPW; ++it) {
    int dl = wv * 8 + it * DPW + sub;      // local dst 0..63 (exclusive per wave)
    int d = node0 + dl;
    int4 q = make_int4(0, 0, 0, 0);
    if (d < NN) q = *(const int4*)(rs4 + (size_t)4 * d);
    const int q0 = q.x, q1 = q.y, q2 = q.z, q3 = q.w;
    float4 a0 = make_float4(0.f, 0.f, 0.f, 0.f);
    float4 a1 = make_float4(0.f, 0.f, 0.f, 0.f);
    float4 a2 = make_float4(0.f, 0.f, 0.f, 0.f);
    for (int base = q0; base < q3; base += SW) {
      int epv = ep[base + sl];             // whole chunk's edge IDs, 1 load
      int pend = (base + SW < q3) ? base + SW : q3;
#pragma unroll 8
      for (int p = base; p < pend; p += EPI) {
        int idx = p + es;
        bool val = idx < pend;
        int srcLane = subBase | ((idx - base) & (SW - 1));
        int e = __shfl(epv, srcLane, 64);
        float4 v = *(const float4*)(x + (size_t)e * IN + k4 * 4);
        float m0 = (val && idx < q1) ? 1.f : 0.f;
        float m1 = (val && idx >= q1 && idx < q2) ? 1.f : 0.f;
        float m2 = (val && idx >= q2) ? 1.f : 0.f;
        a0.x = fmaf(m0, v.x, a0.x); a0.y = fmaf(m0, v.y, a0.y);
        a0.z = fmaf(m0, v.z, a0.z); a0.w = fmaf(m0, v.w, a0.w);
        a1.x = fmaf(m1, v.x, a1.x); a1.y = fmaf(m1, v.y, a1.y);
        a1.z = fmaf(m1, v.z, a1.z); a1.w = fmaf(m1, v.w, a1.w);
        a2.x = fmaf(m2, v.x, a2.x); a2.y = fmaf(m2, v.y, a2.y);
        a2.z = fmaf(m2, v.z, a2.z); a2.w = fmaf(m2, v.w, a2.w);
      }
    }
#pragma unroll
    for (int off = LPE; off < SW; off <<= 1) {
      a0.x += __shfl_xor(a0.x, off, 64); a0.y += __shfl_xor(a0.y, off, 64);
      a0.z += __shfl_xor(a0.z, off, 64); a0.w += __shfl_xor(a0.w, off, 64);
      a1.x += __shfl_xor(a1.x, off, 64); a1.y += __shfl_xor(a1.y, off, 64);
      a1.z += __shfl_xor(a1.z, off, 64); a1.w += __shfl_xor(a1.w, off, 64);
      a2.x += __shfl_xor(a2.x, off, 64); a2.y += __shfl_xor(a2.y, off, 64);
      a2.z += __shfl_xor(a2.z, off, 64); a2.w += __shfl_xor(a2.w, off, 64);
    }
    if (es == 0 && d < NN) {
      float c0 = (float)(q1 - q0 > 0 ? q1 - q0 : 1);
      float c1 = (float)(q2 - q1 > 0 ? q2 - q1 : 1);
      float c2 = (float)(q3 - q2 > 0 ? q3 - q2 : 1);
      int r0 = k4 * 4;
      smem[0 * IN + r0 + 0][dl] = a0.x / c0;
      smem[0 * IN + r0 + 1][dl] = a0.y / c0;
      smem[0 * IN + r0 + 2][dl] = a0.z / c0;
      smem[0 * IN + r0 + 3][dl] = a0.w / c0;
      smem[1 * IN + r0 + 0][dl] = a1.x / c1;
      smem[1 * IN + r0 + 1][dl] = a1.y / c1;
      smem[1 * IN + r0 + 2][dl] = a1.z / c1;
      smem[1 * IN + r0 + 3][dl] = a1.w / c1;
      if constexpr (IN == 32) {
        smem[2 * IN + r0 + 0][dl] = a2.x / c2;
        smem[2 * IN + r0 + 1][dl] = a2.y / c2;
        smem[2 * IN + r0 + 2][dl] = a2.z / c2;
        smem[2 * IN + r0 + 3][dl] = a2.w / c2;
      } else {
        float4 o2;
        o2.x = a2.x / c2; o2.y = a2.y / c2; o2.z = a2.z / c2; o2.w = a2.w / c2;
        *(float4*)(h2 + (size_t)d * IN + r0) = o2;   // coalesced 256B per dst
      }
    }
  }
  __syncthreads();

  // ================= Phase B: dense =================
  const int n = lane;
  const int j0 = __builtin_amdgcn_readfirstlane(wv * 8);
  constexpr int F4 = IN / 4;
  constexpr int NPF = (64 * F4) / 512;   // prefetch float4 per thread (2 or 1)

  float4 pf[NPF];
  int s_nn[NPF], s_c4[NPF];
#pragma unroll
  for (int u = 0; u < NPF; ++u) {
    int idx = u * 512 + tid;
    s_nn[u] = idx / F4;
    s_c4[u] = idx % F4;
  }

  float acc[8];
#pragma unroll
  for (int j = 0; j < 8; ++j) acc[j] = bias[j0 + j];

  auto mm = [&](const float* __restrict__ W, int row0) {
#pragma unroll 4
    for (int k = 0; k < IN; ++k) {
      float sk = smem[row0 + k][n];
      const float* w = W + (size_t)k * 64 + j0;
#pragma unroll
      for (int j = 0; j < 8; ++j) acc[j] = fmaf(sk, w[j], acc[j]);
    }
  };

  if constexpr (IN == 32) {
    // 3-stream path: all means in LDS; prefetch x, run all 3 rel-mm's,
    // one rotation for the root term.
#pragma unroll
    for (int u = 0; u < NPF; ++u) {
      int node = node0 + s_nn[u];
      pf[u] = make_float4(0.f, 0.f, 0.f, 0.f);
      if (node < NN) pf[u] = *(const float4*)(x + (size_t)node * IN + s_c4[u] * 4);
    }
    mm(rel, 0);                             // mean0 @ rel0
    mm(rel + (size_t)IN * 64, IN);          // mean1 @ rel1
    mm(rel + (size_t)2 * IN * 64, 2 * IN);  // mean2 @ rel2
    __syncthreads();                        // all mean rows consumed
#pragma unroll
    for (int u = 0; u < NPF; ++u) {
      int c4 = s_c4[u], nn = s_nn[u];
      smem[c4 * 4 + 0][nn] = pf[u].x;
      smem[c4 * 4 + 1][nn] = pf[u].y;
      smem[c4 * 4 + 2][nn] = pf[u].z;
      smem[c4 * 4 + 3][nn] = pf[u].w;
    }
    __syncthreads();
    mm(root, 0);                            // x @ root
  } else {
    // 2-stream + h2 spill path (R16/R18 measured-best, unchanged)
#pragma unroll
    for (int u = 0; u < NPF; ++u) {
      int node = node0 + s_nn[u];
      pf[u] = make_float4(0.f, 0.f, 0.f, 0.f);
      if (node < NN) pf[u] = *(const float4*)(h2 + (size_t)node * IN + s_c4[u] * 4);
    }
    mm(rel, 0);                             // mean0 @ rel0   (rows [0,IN))
    mm(rel + (size_t)IN * 64, IN);          // mean1 @ rel1   (rows [IN,2IN))
    __syncthreads();                        // rows[0,IN) free
#pragma unroll
    for (int u = 0; u < NPF; ++u) {
      int c4 = s_c4[u], nn = s_nn[u];
      smem[c4 * 4 + 0][nn] = pf[u].x;
      smem[c4 * 4 + 1][nn] = pf[u].y;
      smem[c4 * 4 + 2][nn] = pf[u].z;
      smem[c4 * 4 + 3][nn] = pf[u].w;
    }
#pragma unroll
    for (int u = 0; u < NPF; ++u) {
      int node = node0 + s_nn[u];
      pf[u] = make_float4(0.f, 0.f, 0.f, 0.f);
      if (node < NN) pf[u] = *(const float4*)(x + (size_t)node * IN + s_c4[u] * 4);
    }
    __syncthreads();
    mm(rel + (size_t)2 * IN * 64, 0);       // mean2 @ rel2   (rows [0,IN))
    __syncthreads();                        // rows[IN,2IN) free
#pragma unroll
    for (int u = 0; u < NPF; ++u) {
      int c4 = s_c4[u], nn = s_nn[u];
      smem[IN + c4 * 4 + 0][nn] = pf[u].x;
      smem[IN + c4 * 4 + 1][nn] = pf[u].y;
      smem[IN + c4 * 4 + 2][nn] = pf[u].z;
      smem[IN + c4 * 4 + 3][nn] = pf[u].w;
    }
    __syncthreads();
    mm(root, IN);                           // x @ root       (rows [IN,2IN))
  }

  int node = node0 + n;
  if (node < NN) {
    float4* o = (float4*)(y + (size_t)node * 64 + j0);
    float4 v;
    v.x = fmaxf(acc[0], 0.f); v.y = fmaxf(acc[1], 0.f);
    v.z = fmaxf(acc[2], 0.f); v.w = fmaxf(acc[3], 0.f);
    o[0] = v;
    v.x = fmaxf(acc[4], 0.f); v.y = fmaxf(acc[5], 0.f);
    v.z = fmaxf(acc[6], 0.f); v.w = fmaxf(acc[7], 0.f);
    o[1] = v;
  }
}

// ---------- mean pool over sorted batch ids (run-length reduce, then atomic) ----------
__global__ __launch_bounds__(256) void k_pool(
    const float* __restrict__ x3, const int* __restrict__ batch,
    float* __restrict__ pooled, float* __restrict__ gcnt)
{
  int gwave = (blockIdx.x * 256 + threadIdx.x) >> 6;
  int lane = threadIdx.x & 63;
  int n0 = gwave * 64;
  if (n0 >= NN) return;
  int n1 = n0 + 64 < NN ? n0 + 64 : NN;
  int gcur = batch[n0];
  float acc = 0.f;
  int run = 0;
  for (int n = n0; n < n1; ++n) {
    int g = batch[n];
    if (g != gcur) {
      atomicAdd(&pooled[gcur * 64 + lane], acc);
      if (lane == 0) atomicAdd(&gcnt[gcur], (float)run);
      acc = 0.f; run = 0; gcur = g;
    }
    acc += x3[(size_t)n * 64 + lane];
    ++run;
  }
  atomicAdd(&pooled[gcur * 64 + lane], acc);
  if (lane == 0) atomicAdd(&gcnt[gcur], (float)run);
}

// ---------- classifier ----------
__global__ __launch_bounds__(256) void k_cls(
    const float* __restrict__ pooled, const float* __restrict__ gcnt,
    const float* __restrict__ cw, const float* __restrict__ cb, float* __restrict__ out)
{
  int t = blockIdx.x * 256 + threadIdx.x;
  if (t >= NG * 10) return;
  int g = t / 10, c = t % 10;
  float cf = fmaxf(gcnt[g], 1.f);
  float acc = cb[c];
#pragma unroll 8
  for (int k = 0; k < 64; ++k)
    acc += (pooled[g * 64 + k] / cf) * cw[k * 10 + c];
  out[t] = acc;
}

extern "C" void kernel_launch(void* const* d_in, const int* in_sizes, int n_in,
                              void* d_out, int out_size, void* d_ws, size_t ws_size,
                              hipStream_t stream)
{
  const int* nf = (const int*)d_in[0];
  const int* ei = (const int*)d_in[1];
  const int* et = (const int*)d_in[2];
  const int* batch = (const int*)d_in[3];
  const float* semb = (const float*)d_in[4];
  const float* cemb = (const float*)d_in[5];
  const float* pw = (const float*)d_in[6];
  const float* pb = (const float*)d_in[7];
  const float* root1 = (const float*)d_in[8];
  const float* rel1 = (const float*)d_in[9];
  const float* bias1 = (const float*)d_in[10];
  const float* root2 = (const float*)d_in[11];
  const float* rel2 = (const float*)d_in[12];
  const float* bias2 = (const float*)d_in[13];
  const float* cw = (const float*)d_in[14];
  const float* cb = (const float*)d_in[15];
  float* out = (float*)d_out;

  char* ws = (char*)d_ws;
  size_t off = 0;
  auto alloc = [&](size_t bytes) {
    char* p = ws + off;
    off += (bytes + 255) & ~(size_t)255;
    return p;
  };
  int* bkt_cur = (int*)alloc((size_t)NB * 4);
  int* rs4 = (int*)alloc((size_t)NN * 4 * 4);             // per-node run bounds (int4)
  int* ep = (int*)alloc(((size_t)NB * CAPB + 64) * 4);    // padded-bucket, type-sorted
  int* binned = (int*)alloc((size_t)NB * CAPB * 4);       // binning scratch
  float* h2 = (float*)alloc((size_t)NN * 64 * 4);         // mean2 spill (IN=64 only)
  float* xA = (float*)alloc((size_t)NN * 64 * 4);         // x2
  float* xB = (float*)alloc((size_t)NN * 64 * 4);         // x1 ([N,32]) then x3
  float* pooled = (float*)alloc((size_t)NG * 64 * 4);
  float* gcnt = (float*)alloc((size_t)NG * 4);
  (void)ws_size; (void)in_sizes; (void)n_in; (void)out_size;

  hipMemsetAsync(bkt_cur, 0, (size_t)NB * 4, stream);
  // zero ep so gap/pad slots read as src=0 (masked by w=0 in the gather)
  hipMemsetAsync(ep, 0, ((size_t)NB * CAPB + 64) * 4, stream);
  k_embed<<<(NN + 255) / 256, 256, 0, stream>>>(nf, semb, cemb, pw, pb, xB);

  // CSR build: padded-bucket counting sort (no count/scan pass)
  kA_scatter<<<NAB, 256, 0, stream>>>(ei, et, bkt_cur, binned);
  kB_build<<<NB, 512, 0, stream>>>(bkt_cur, binned, rs4, ep);

  int fgrid = (NN + 63) / 64;  // 1563 blocks, 64 dsts each

  // layer 1: x1 (xB) -> x2 (xA);  layer 2: x2 (xA) -> x3 (xB)
  k_fused<32><<<fgrid, 512, 0, stream>>>(xB, rs4, ep, root1, rel1, bias1, h2, xA);
  k_fused<64><<<fgrid, 512, 0, stream>>>(xA, rs4, ep, root2, rel2, bias2, h2, xB);

  hipMemsetAsync(pooled, 0, (size_t)NG * 64 * 4, stream);
  hipMemsetAsync(gcnt, 0, (size_t)NG * 4, stream);
  int nwaves = (NN + 63) / 64;
  k_pool<<<(nwaves + 3) / 4, 256, 0, stream>>>(xB, batch, pooled, gcnt);
  k_cls<<<(NG * 10 + 255) / 256, 256, 0, stream>>>(pooled, gcnt, cw, cb, out);
}